// Round 1
// baseline (8638.893 us; speedup 1.0000x reference)
//
#include <hip/hip_runtime.h>

#define N_NODES 50000
#define N_EDGES 800000
#define IN_DIM 128
#define HID 256
#define N_CLASSES 10
#define N_GRAPHS 64
#define BN_EPS 1e-5f

// ---------------------------------------------------------------- utilities
__global__ __launch_bounds__(256) void zero_f4(float4* __restrict__ p, int n4) {
    int i = blockIdx.x * blockDim.x + threadIdx.x;
    int stride = gridDim.x * blockDim.x;
    for (; i < n4; i += stride) p[i] = make_float4(0.f, 0.f, 0.f, 0.f);
}

__global__ __launch_bounds__(256) void init_deg(float* __restrict__ dis) {
    int i = blockIdx.x * blockDim.x + threadIdx.x;
    if (i < N_NODES) dis[i] = 1.0f;
}

__global__ __launch_bounds__(256) void deg_accum(const int* __restrict__ dst,
                                                 float* __restrict__ dis) {
    int e = blockIdx.x * blockDim.x + threadIdx.x;
    if (e < N_EDGES) atomicAdd(&dis[dst[e]], 1.0f);
}

__global__ __launch_bounds__(256) void deg_rsqrt(float* __restrict__ dis) {
    int i = blockIdx.x * blockDim.x + threadIdx.x;
    if (i < N_NODES) dis[i] = rsqrtf(dis[i]);
}

// ---------------------------------------------------------------- GEMM
// out[r][c] = (sum_k A[r][k] * W[k][c]) * dis[r]
// 64x64 tile, BK=16, 256 threads, 4x4 per thread. As stored transposed.
__global__ __launch_bounds__(256) void gemm_rowscale(
    const float* __restrict__ A, const float* __restrict__ W,
    const float* __restrict__ dis, float* __restrict__ out, int M, int K)
{
    __shared__ float As[16][68];  // [kk][row], pad 68 (272B stride, 16B-aligned)
    __shared__ float Bs[16][68];  // [kk][col]

    const int t  = threadIdx.x;
    const int tx = t & 15;
    const int ty = t >> 4;
    const int row0 = blockIdx.x * 64;
    const int col0 = blockIdx.y * 64;

    float acc[4][4] = {};

    const int ar = t >> 2;        // 0..63  (A tile row)
    const int ac = (t & 3) * 4;   // 0,4,8,12 (A tile k)
    const int br = t >> 4;        // 0..15  (B tile k)
    const int bc = (t & 15) * 4;  // 0..60  (B tile col)

    for (int k0 = 0; k0 < K; k0 += 16) {
        float4 av = make_float4(0.f, 0.f, 0.f, 0.f);
        int gr = row0 + ar;
        if (gr < M) av = *(const float4*)(A + (size_t)gr * K + k0 + ac);
        As[ac + 0][ar] = av.x;
        As[ac + 1][ar] = av.y;
        As[ac + 2][ar] = av.z;
        As[ac + 3][ar] = av.w;

        float4 bv = *(const float4*)(W + (size_t)(k0 + br) * HID + col0 + bc);
        *(float4*)&Bs[br][bc] = bv;

        __syncthreads();
#pragma unroll
        for (int kk = 0; kk < 16; ++kk) {
            float4 a = *(const float4*)&As[kk][ty * 4];
            float4 b = *(const float4*)&Bs[kk][tx * 4];
            acc[0][0] = fmaf(a.x, b.x, acc[0][0]);
            acc[0][1] = fmaf(a.x, b.y, acc[0][1]);
            acc[0][2] = fmaf(a.x, b.z, acc[0][2]);
            acc[0][3] = fmaf(a.x, b.w, acc[0][3]);
            acc[1][0] = fmaf(a.y, b.x, acc[1][0]);
            acc[1][1] = fmaf(a.y, b.y, acc[1][1]);
            acc[1][2] = fmaf(a.y, b.z, acc[1][2]);
            acc[1][3] = fmaf(a.y, b.w, acc[1][3]);
            acc[2][0] = fmaf(a.z, b.x, acc[2][0]);
            acc[2][1] = fmaf(a.z, b.y, acc[2][1]);
            acc[2][2] = fmaf(a.z, b.z, acc[2][2]);
            acc[2][3] = fmaf(a.z, b.w, acc[2][3]);
            acc[3][0] = fmaf(a.w, b.x, acc[3][0]);
            acc[3][1] = fmaf(a.w, b.y, acc[3][1]);
            acc[3][2] = fmaf(a.w, b.z, acc[3][2]);
            acc[3][3] = fmaf(a.w, b.w, acc[3][3]);
        }
        __syncthreads();
    }

#pragma unroll
    for (int i = 0; i < 4; ++i) {
        int r = row0 + ty * 4 + i;
        if (r < M) {
            float d = dis[r];
            float4 o = make_float4(acc[i][0] * d, acc[i][1] * d,
                                   acc[i][2] * d, acc[i][3] * d);
            *(float4*)(out + (size_t)r * HID + col0 + tx * 4) = o;
        }
    }
}

// ---------------------------------------------------------------- scatter
// One wave per edge: s[dst] += ht[src]  (256 channels, lane holds 4)
__global__ __launch_bounds__(256) void scatter_edges(
    const float* __restrict__ ht, const int* __restrict__ src,
    const int* __restrict__ dst, float* __restrict__ s)
{
    long long gid = (long long)blockIdx.x * blockDim.x + threadIdx.x;
    int e = (int)(gid >> 6);
    int lane = (int)(gid & 63);
    if (e >= N_EDGES) return;
    int u = src[e];
    int v = dst[e];
    float4 val = *(const float4*)(ht + (size_t)u * HID + lane * 4);
    float* p = s + (size_t)v * HID + lane * 4;
    atomicAdd(p + 0, val.x);
    atomicAdd(p + 1, val.y);
    atomicAdd(p + 2, val.z);
    atomicAdd(p + 3, val.w);
}

// ---------------------------------------------------------------- finalize
// s[n][c] = relu(dis[n] * (s[n][c] + ht[n][c]) + b[c])   (in place into s)
__global__ __launch_bounds__(256) void finalize_relu(
    float* __restrict__ s, const float* __restrict__ ht,
    const float* __restrict__ dis, const float* __restrict__ b)
{
    int idx = blockIdx.x * blockDim.x + threadIdx.x;  // float4 index
    const int total = N_NODES * (HID / 4);
    if (idx >= total) return;
    int n  = idx >> 6;
    int c4 = idx & 63;
    float d = dis[n];
    float4 sv = ((float4*)s)[idx];
    float4 hv = ((const float4*)ht)[idx];
    float4 bv = ((const float4*)b)[c4];
    float4 o;
    o.x = fmaxf(fmaf(d, sv.x + hv.x, bv.x), 0.f);
    o.y = fmaxf(fmaf(d, sv.y + hv.y, bv.y), 0.f);
    o.z = fmaxf(fmaf(d, sv.z + hv.z, bv.z), 0.f);
    o.w = fmaxf(fmaf(d, sv.w + hv.w, bv.w), 0.f);
    ((float4*)s)[idx] = o;
}

// ---------------------------------------------------------------- batch norm
__global__ __launch_bounds__(256) void bn_stats(
    const float* __restrict__ h, float* __restrict__ stats, int rows_per_block)
{
    int c  = threadIdx.x;             // channel 0..255
    int r0 = blockIdx.x * rows_per_block;
    int r1 = min(r0 + rows_per_block, N_NODES);
    if (r0 >= N_NODES) return;
    float sum = 0.f, sq = 0.f;
    for (int r = r0; r < r1; ++r) {
        float v = h[(size_t)r * HID + c];
        sum += v;
        sq  = fmaf(v, v, sq);
    }
    atomicAdd(&stats[c], sum);
    atomicAdd(&stats[HID + c], sq);
}

__global__ __launch_bounds__(256) void bn_apply(
    float* __restrict__ h, const float* __restrict__ stats,
    const float* __restrict__ g, const float* __restrict__ be)
{
    int idx = blockIdx.x * blockDim.x + threadIdx.x;  // float4 index
    const int total = N_NODES * (HID / 4);
    if (idx >= total) return;
    int c4 = idx & 63;
    const float invN = 1.0f / N_NODES;
    float4 sm = ((const float4*)stats)[c4];
    float4 sq = ((const float4*)(stats + HID))[c4];
    float4 gv = ((const float4*)g)[c4];
    float4 bv = ((const float4*)be)[c4];
    float4 v  = ((float4*)h)[idx];
    float4 o;
    float mu, var, sc;
    mu = sm.x * invN; var = sq.x * invN - mu * mu; sc = rsqrtf(var + BN_EPS) * gv.x;
    o.x = (v.x - mu) * sc + bv.x;
    mu = sm.y * invN; var = sq.y * invN - mu * mu; sc = rsqrtf(var + BN_EPS) * gv.y;
    o.y = (v.y - mu) * sc + bv.y;
    mu = sm.z * invN; var = sq.z * invN - mu * mu; sc = rsqrtf(var + BN_EPS) * gv.z;
    o.z = (v.z - mu) * sc + bv.z;
    mu = sm.w * invN; var = sq.w * invN - mu * mu; sc = rsqrtf(var + BN_EPS) * gv.w;
    o.w = (v.w - mu) * sc + bv.w;
    ((float4*)h)[idx] = o;
}

// ---------------------------------------------------------------- pooling
__global__ __launch_bounds__(256) void pool_accum(
    const float* __restrict__ h, const int* __restrict__ batch,
    float* __restrict__ pool, float* __restrict__ cnt, int rows_per_block)
{
    int c  = threadIdx.x;
    int r0 = blockIdx.x * rows_per_block;
    int r1 = min(r0 + rows_per_block, N_NODES);
    if (r0 >= N_NODES) return;
    float acc = 0.f;
    int curg = batch[r0];
    for (int r = r0; r < r1; ++r) {
        int gidx = batch[r];
        if (gidx != curg) {
            atomicAdd(&pool[(size_t)curg * HID + c], acc);
            acc = 0.f;
            curg = gidx;
        }
        acc += h[(size_t)r * HID + c];
    }
    atomicAdd(&pool[(size_t)curg * HID + c], acc);
    if (c == 0) {
        int cacc = 0;
        int cg = batch[r0];
        for (int r = r0; r < r1; ++r) {
            int gidx = batch[r];
            if (gidx != cg) { atomicAdd(&cnt[cg], (float)cacc); cacc = 0; cg = gidx; }
            cacc++;
        }
        atomicAdd(&cnt[cg], (float)cacc);
    }
}

__global__ __launch_bounds__(256) void final_head(
    const float* __restrict__ pool, const float* __restrict__ cnt,
    const float* __restrict__ Wf, const float* __restrict__ bf,
    float* __restrict__ out)
{
    __shared__ float p[HID];
    int g = blockIdx.x;
    int c = threadIdx.x;
    float inv = 1.0f / fmaxf(cnt[g], 1.0f);
    p[c] = pool[(size_t)g * HID + c] * inv;
    __syncthreads();
    if (c < N_CLASSES) {
        float acc = bf[c];
        for (int k = 0; k < HID; ++k) acc = fmaf(p[k], Wf[k * N_CLASSES + c], acc);
        out[g * N_CLASSES + c] = acc;
    }
}

// ---------------------------------------------------------------- launch
extern "C" void kernel_launch(void* const* d_in, const int* in_sizes, int n_in,
                              void* d_out, int out_size, void* d_ws, size_t ws_size,
                              hipStream_t stream) {
    const float* x   = (const float*)d_in[0];
    const int* eidx  = (const int*)d_in[1];
    const int* batch = (const int*)d_in[2];
    const float* W1  = (const float*)d_in[3];
    const float* b1  = (const float*)d_in[4];
    const float* W2  = (const float*)d_in[5];
    const float* b2  = (const float*)d_in[6];
    const float* W3  = (const float*)d_in[7];
    const float* b3  = (const float*)d_in[8];
    const float* g1  = (const float*)d_in[9];
    const float* be1 = (const float*)d_in[10];
    const float* g2  = (const float*)d_in[11];
    const float* be2 = (const float*)d_in[12];
    const float* Wf  = (const float*)d_in[13];
    const float* bf  = (const float*)d_in[14];
    float* out = (float*)d_out;

    const int* src = eidx;
    const int* dst = eidx + N_EDGES;

    // workspace layout
    float* ht    = (float*)d_ws;                    // 50000*256
    float* s     = ht + (size_t)N_NODES * HID;      // 50000*256
    float* dis   = s + (size_t)N_NODES * HID;       // 50000
    float* stats = dis + N_NODES;                   // 512
    float* pool  = stats + 2 * HID;                 // 64*256
    float* cnt   = pool + (size_t)N_GRAPHS * HID;   // 64

    const int feat4    = N_NODES * (HID / 4);       // float4 count of a feature buf
    const int featBlk  = (feat4 + 255) / 256;
    const int mTiles   = (N_NODES + 63) / 64;       // 782
    dim3 gemmGrid(mTiles, HID / 64);
    const int scatterBlocks = (int)(((long long)N_EDGES * 64 + 255) / 256);
    const int rowsPerBlock  = (N_NODES + 255) / 256; // 196

    // degrees
    init_deg<<<(N_NODES + 255) / 256, 256, 0, stream>>>(dis);
    deg_accum<<<(N_EDGES + 255) / 256, 256, 0, stream>>>(dst, dis);
    deg_rsqrt<<<(N_NODES + 255) / 256, 256, 0, stream>>>(dis);

    // ---- layer 1: x @ W1 -> aggregate -> relu
    gemm_rowscale<<<gemmGrid, 256, 0, stream>>>(x, W1, dis, ht, N_NODES, IN_DIM);
    zero_f4<<<featBlk, 256, 0, stream>>>((float4*)s, feat4);
    scatter_edges<<<scatterBlocks, 256, 0, stream>>>(ht, src, dst, s);
    finalize_relu<<<featBlk, 256, 0, stream>>>(s, ht, dis, b1);

    // ---- layer 2: s @ W2 -> aggregate -> relu -> BN1
    gemm_rowscale<<<gemmGrid, 256, 0, stream>>>(s, W2, dis, ht, N_NODES, HID);
    zero_f4<<<featBlk, 256, 0, stream>>>((float4*)s, feat4);
    scatter_edges<<<scatterBlocks, 256, 0, stream>>>(ht, src, dst, s);
    finalize_relu<<<featBlk, 256, 0, stream>>>(s, ht, dis, b2);
    zero_f4<<<1, 256, 0, stream>>>((float4*)stats, 2 * HID / 4);
    bn_stats<<<256, 256, 0, stream>>>(s, stats, rowsPerBlock);
    bn_apply<<<featBlk, 256, 0, stream>>>(s, stats, g1, be1);

    // ---- layer 3: s @ W3 -> aggregate -> relu -> BN2
    gemm_rowscale<<<gemmGrid, 256, 0, stream>>>(s, W3, dis, ht, N_NODES, HID);
    zero_f4<<<featBlk, 256, 0, stream>>>((float4*)s, feat4);
    scatter_edges<<<scatterBlocks, 256, 0, stream>>>(ht, src, dst, s);
    finalize_relu<<<featBlk, 256, 0, stream>>>(s, ht, dis, b3);
    zero_f4<<<1, 256, 0, stream>>>((float4*)stats, 2 * HID / 4);
    bn_stats<<<256, 256, 0, stream>>>(s, stats, rowsPerBlock);
    bn_apply<<<featBlk, 256, 0, stream>>>(s, stats, g2, be2);

    // ---- pool + head
    zero_f4<<<(N_GRAPHS * HID / 4 + N_GRAPHS / 4 + 255) / 256, 256, 0, stream>>>(
        (float4*)pool, N_GRAPHS * HID / 4 + N_GRAPHS / 4);
    pool_accum<<<256, 256, 0, stream>>>(s, batch, pool, cnt, rowsPerBlock);
    final_head<<<N_GRAPHS, 256, 0, stream>>>(pool, cnt, Wf, bf, out);
}

// Round 8
// 1002.926 us; speedup vs baseline: 8.6137x; 8.6137x over previous
//
#include <hip/hip_runtime.h>

#define N_NODES 50000
#define N_EDGES 800000
#define IN_DIM 128
#define HID 256
#define N_CLASSES 10
#define N_GRAPHS 64
#define BN_EPS 1e-5f
#define NCHUNK ((N_NODES + 255) / 256)   // 196

// ---------------------------------------------------------------- utilities
__global__ __launch_bounds__(256) void zero_f4(float4* __restrict__ p, int n4) {
    int i = blockIdx.x * blockDim.x + threadIdx.x;
    int stride = gridDim.x * blockDim.x;
    for (; i < n4; i += stride) p[i] = make_float4(0.f, 0.f, 0.f, 0.f);
}

// ---------------------------------------------------------------- CSR build
__global__ __launch_bounds__(256) void count_deg(const int* __restrict__ dst,
                                                 int* __restrict__ deg) {
    int e = blockIdx.x * blockDim.x + threadIdx.x;
    if (e < N_EDGES) atomicAdd(&deg[dst[e]], 1);
}

__global__ __launch_bounds__(256) void deg_to_dis(const int* __restrict__ deg,
                                                  float* __restrict__ dis) {
    int i = blockIdx.x * blockDim.x + threadIdx.x;
    if (i < N_NODES) dis[i] = rsqrtf(1.0f + (float)deg[i]);
}

// per-chunk exclusive scan; chunk totals out
__global__ __launch_bounds__(256) void scan_chunk(const int* __restrict__ deg,
                                                  int* __restrict__ row_start,
                                                  int* __restrict__ chunk_sums) {
    __shared__ int buf[256];
    int t = threadIdx.x;
    int i = blockIdx.x * 256 + t;
    int v = (i < N_NODES) ? deg[i] : 0;
    buf[t] = v;
    __syncthreads();
#pragma unroll
    for (int off = 1; off < 256; off <<= 1) {
        int tmp = (t >= off) ? buf[t - off] : 0;
        __syncthreads();
        buf[t] += tmp;
        __syncthreads();
    }
    if (i < N_NODES) row_start[i] = buf[t] - v;  // exclusive
    if (t == 255) chunk_sums[blockIdx.x] = buf[255];
}

// single-block exclusive scan of chunk sums
__global__ __launch_bounds__(256) void scan_tops(int* __restrict__ chunk_sums) {
    __shared__ int buf[256];
    int t = threadIdx.x;
    int v = (t < NCHUNK) ? chunk_sums[t] : 0;
    buf[t] = v;
    __syncthreads();
#pragma unroll
    for (int off = 1; off < 256; off <<= 1) {
        int tmp = (t >= off) ? buf[t - off] : 0;
        __syncthreads();
        buf[t] += tmp;
        __syncthreads();
    }
    if (t < NCHUNK) chunk_sums[t] = buf[t] - v;  // exclusive
}

__global__ __launch_bounds__(256) void scan_add(int* __restrict__ row_start,
                                                const int* __restrict__ chunk_sums) {
    int i = blockIdx.x * blockDim.x + threadIdx.x;
    if (i < N_NODES) row_start[i] += chunk_sums[i >> 8];
}

// fill buckets; destructively advances row_start -> end pointers
__global__ __launch_bounds__(256) void fill_adj(const int* __restrict__ src,
                                                const int* __restrict__ dst,
                                                int* __restrict__ row_start,
                                                int* __restrict__ adj) {
    int e = blockIdx.x * blockDim.x + threadIdx.x;
    if (e < N_EDGES) {
        int pos = atomicAdd(&row_start[dst[e]], 1);
        pos = min(pos, N_EDGES - 1);   // no-op when scan correct; fault guard
        adj[pos] = src[e];
    }
}

// ---------------------------------------------------------------- GEMM
// out[r][c] = (sum_k A[r][k] * W[k][c]) * dis[r]
__global__ __launch_bounds__(256) void gemm_rowscale(
    const float* __restrict__ A, const float* __restrict__ W,
    const float* __restrict__ dis, float* __restrict__ out, int M, int K)
{
    __shared__ float As[16][68];
    __shared__ float Bs[16][68];

    const int t  = threadIdx.x;
    const int tx = t & 15;
    const int ty = t >> 4;
    const int row0 = blockIdx.x * 64;
    const int col0 = blockIdx.y * 64;

    float acc[4][4] = {};

    const int ar = t >> 2;
    const int ac = (t & 3) * 4;
    const int br = t >> 4;
    const int bc = (t & 15) * 4;

    for (int k0 = 0; k0 < K; k0 += 16) {
        float4 av = make_float4(0.f, 0.f, 0.f, 0.f);
        int gr = row0 + ar;
        if (gr < M) av = *(const float4*)(A + (size_t)gr * K + k0 + ac);
        As[ac + 0][ar] = av.x;
        As[ac + 1][ar] = av.y;
        As[ac + 2][ar] = av.z;
        As[ac + 3][ar] = av.w;

        float4 bv = *(const float4*)(W + (size_t)(k0 + br) * HID + col0 + bc);
        *(float4*)&Bs[br][bc] = bv;

        __syncthreads();
#pragma unroll
        for (int kk = 0; kk < 16; ++kk) {
            float4 a = *(const float4*)&As[kk][ty * 4];
            float4 b = *(const float4*)&Bs[kk][tx * 4];
            acc[0][0] = fmaf(a.x, b.x, acc[0][0]);
            acc[0][1] = fmaf(a.x, b.y, acc[0][1]);
            acc[0][2] = fmaf(a.x, b.z, acc[0][2]);
            acc[0][3] = fmaf(a.x, b.w, acc[0][3]);
            acc[1][0] = fmaf(a.y, b.x, acc[1][0]);
            acc[1][1] = fmaf(a.y, b.y, acc[1][1]);
            acc[1][2] = fmaf(a.y, b.z, acc[1][2]);
            acc[1][3] = fmaf(a.y, b.w, acc[1][3]);
            acc[2][0] = fmaf(a.z, b.x, acc[2][0]);
            acc[2][1] = fmaf(a.z, b.y, acc[2][1]);
            acc[2][2] = fmaf(a.z, b.z, acc[2][2]);
            acc[2][3] = fmaf(a.z, b.w, acc[2][3]);
            acc[3][0] = fmaf(a.w, b.x, acc[3][0]);
            acc[3][1] = fmaf(a.w, b.y, acc[3][1]);
            acc[3][2] = fmaf(a.w, b.z, acc[3][2]);
            acc[3][3] = fmaf(a.w, b.w, acc[3][3]);
        }
        __syncthreads();
    }

#pragma unroll
    for (int i = 0; i < 4; ++i) {
        int r = row0 + ty * 4 + i;
        if (r < M) {
            float d = dis[r];
            float4 o = make_float4(acc[i][0] * d, acc[i][1] * d,
                                   acc[i][2] * d, acc[i][3] * d);
            *(float4*)(out + (size_t)r * HID + col0 + tx * 4) = o;
        }
    }
}

// ---------------------------------------------------------------- gather
// One wave per node: s[n] = relu(dis[n]*(sum_{u in adj(n)} ht[u] + ht[n]) + b)
// row_end[n] = end of bucket n (row_start after fill); beg = row_end[n-1].
__global__ __launch_bounds__(256) void gather_relu(
    const float* __restrict__ ht, const int* __restrict__ row_end,
    const int* __restrict__ adj, const float* __restrict__ dis,
    const float* __restrict__ b, float* __restrict__ s)
{
    int wid  = (blockIdx.x * 256 + threadIdx.x) >> 6;  // node id
    int lane = threadIdx.x & 63;
    if (wid >= N_NODES) return;
    const int n = wid;
    const int c = lane * 4;
    int beg = (n == 0) ? 0 : row_end[n - 1];
    int end = row_end[n];

    float4 acc = *(const float4*)(ht + (size_t)n * HID + c);  // self loop

    int j = beg;
    while (j < end) {
        int m = end - j;
        if (m > 64) m = 64;
        int ul = adj[j + (lane < m ? lane : m - 1)];
        ul = min(ul, N_NODES - 1);   // no-op when adj valid; fault guard
        int k = 0;
        for (; k + 1 < m; k += 2) {
            int u0 = __shfl(ul, k);
            int u1 = __shfl(ul, k + 1);
            float4 v0 = *(const float4*)(ht + (size_t)u0 * HID + c);
            float4 v1 = *(const float4*)(ht + (size_t)u1 * HID + c);
            acc.x += v0.x + v1.x;
            acc.y += v0.y + v1.y;
            acc.z += v0.z + v1.z;
            acc.w += v0.w + v1.w;
        }
        if (k < m) {
            int u0 = __shfl(ul, k);
            float4 v0 = *(const float4*)(ht + (size_t)u0 * HID + c);
            acc.x += v0.x;
            acc.y += v0.y;
            acc.z += v0.z;
            acc.w += v0.w;
        }
        j += m;
    }

    float d = dis[n];
    float4 bv = ((const float4*)b)[lane];
    float4 o;
    o.x = fmaxf(fmaf(d, acc.x, bv.x), 0.f);
    o.y = fmaxf(fmaf(d, acc.y, bv.y), 0.f);
    o.z = fmaxf(fmaf(d, acc.z, bv.z), 0.f);
    o.w = fmaxf(fmaf(d, acc.w, bv.w), 0.f);
    *(float4*)(s + (size_t)n * HID + c) = o;
}

// ---------------------------------------------------------------- batch norm
__global__ __launch_bounds__(256) void bn_stats(
    const float* __restrict__ h, float* __restrict__ stats, int rows_per_block)
{
    int c  = threadIdx.x;
    int r0 = blockIdx.x * rows_per_block;
    int r1 = min(r0 + rows_per_block, N_NODES);
    if (r0 >= N_NODES) return;
    float sum = 0.f, sq = 0.f;
    for (int r = r0; r < r1; ++r) {
        float v = h[(size_t)r * HID + c];
        sum += v;
        sq  = fmaf(v, v, sq);
    }
    atomicAdd(&stats[c], sum);
    atomicAdd(&stats[HID + c], sq);
}

__global__ __launch_bounds__(256) void bn_apply(
    float* __restrict__ h, const float* __restrict__ stats,
    const float* __restrict__ g, const float* __restrict__ be)
{
    int idx = blockIdx.x * blockDim.x + threadIdx.x;
    const int total = N_NODES * (HID / 4);
    if (idx >= total) return;
    int c4 = idx & 63;
    const float invN = 1.0f / N_NODES;
    float4 sm = ((const float4*)stats)[c4];
    float4 sq = ((const float4*)(stats + HID))[c4];
    float4 gv = ((const float4*)g)[c4];
    float4 bv = ((const float4*)be)[c4];
    float4 v  = ((float4*)h)[idx];
    float4 o;
    float mu, var, sc;
    mu = sm.x * invN; var = sq.x * invN - mu * mu; sc = rsqrtf(var + BN_EPS) * gv.x;
    o.x = (v.x - mu) * sc + bv.x;
    mu = sm.y * invN; var = sq.y * invN - mu * mu; sc = rsqrtf(var + BN_EPS) * gv.y;
    o.y = (v.y - mu) * sc + bv.y;
    mu = sm.z * invN; var = sq.z * invN - mu * mu; sc = rsqrtf(var + BN_EPS) * gv.z;
    o.z = (v.z - mu) * sc + bv.z;
    mu = sm.w * invN; var = sq.w * invN - mu * mu; sc = rsqrtf(var + BN_EPS) * gv.w;
    o.w = (v.w - mu) * sc + bv.w;
    ((float4*)h)[idx] = o;
}

// ---------------------------------------------------------------- pooling
__global__ __launch_bounds__(256) void pool_accum(
    const float* __restrict__ h, const int* __restrict__ batch,
    float* __restrict__ pool, float* __restrict__ cnt, int rows_per_block)
{
    int c  = threadIdx.x;
    int r0 = blockIdx.x * rows_per_block;
    int r1 = min(r0 + rows_per_block, N_NODES);
    if (r0 >= N_NODES) return;
    float acc = 0.f;
    int curg = batch[r0];
    for (int r = r0; r < r1; ++r) {
        int gidx = batch[r];
        if (gidx != curg) {
            atomicAdd(&pool[(size_t)curg * HID + c], acc);
            acc = 0.f;
            curg = gidx;
        }
        acc += h[(size_t)r * HID + c];
    }
    atomicAdd(&pool[(size_t)curg * HID + c], acc);
    if (c == 0) {
        int cacc = 0;
        int cg = batch[r0];
        for (int r = r0; r < r1; ++r) {
            int gidx = batch[r];
            if (gidx != cg) { atomicAdd(&cnt[cg], (float)cacc); cacc = 0; cg = gidx; }
            cacc++;
        }
        atomicAdd(&cnt[cg], (float)cacc);
    }
}

__global__ __launch_bounds__(256) void final_head(
    const float* __restrict__ pool, const float* __restrict__ cnt,
    const float* __restrict__ Wf, const float* __restrict__ bf,
    float* __restrict__ out)
{
    __shared__ float p[HID];
    int g = blockIdx.x;
    int c = threadIdx.x;
    float inv = 1.0f / fmaxf(cnt[g], 1.0f);
    p[c] = pool[(size_t)g * HID + c] * inv;
    __syncthreads();
    if (c < N_CLASSES) {
        float acc = bf[c];
        for (int k = 0; k < HID; ++k) acc = fmaf(p[k], Wf[k * N_CLASSES + c], acc);
        out[g * N_CLASSES + c] = acc;
    }
}

// ---------------------------------------------------------------- launch
extern "C" void kernel_launch(void* const* d_in, const int* in_sizes, int n_in,
                              void* d_out, int out_size, void* d_ws, size_t ws_size,
                              hipStream_t stream) {
    const float* x   = (const float*)d_in[0];
    const int* eidx  = (const int*)d_in[1];
    const int* batch = (const int*)d_in[2];
    const float* W1  = (const float*)d_in[3];
    const float* b1  = (const float*)d_in[4];
    const float* W2  = (const float*)d_in[5];
    const float* b2  = (const float*)d_in[6];
    const float* W3  = (const float*)d_in[7];
    const float* b3  = (const float*)d_in[8];
    const float* g1  = (const float*)d_in[9];
    const float* be1 = (const float*)d_in[10];
    const float* g2  = (const float*)d_in[11];
    const float* be2 = (const float*)d_in[12];
    const float* Wf  = (const float*)d_in[13];
    const float* bf  = (const float*)d_in[14];
    float* out = (float*)d_out;

    const int* src = eidx;
    const int* dst = eidx + N_EDGES;

    // workspace layout (~106.3 MB)
    float* ht        = (float*)d_ws;                     // 12.8M f
    float* s         = ht + (size_t)N_NODES * HID;       // 12.8M f
    float* dis       = s + (size_t)N_NODES * HID;        // 50000 f
    float* stats     = dis + N_NODES;                    // 512 f
    float* pool      = stats + 2 * HID;                  // 16384 f
    float* cnt       = pool + (size_t)N_GRAPHS * HID;    // 64 f
    int* deg         = (int*)(cnt + N_GRAPHS);           // 50000 i
    int* row_start   = deg + N_NODES;                    // 50000 i
    int* chunk_sums  = row_start + N_NODES;              // 256 i
    int* adj         = chunk_sums + 256;                 // 800000 i

    const int feat4   = N_NODES * (HID / 4);
    const int featBlk = (feat4 + 255) / 256;
    const int mTiles  = (N_NODES + 63) / 64;
    dim3 gemmGrid(mTiles, HID / 64);
    const int nodeBlk = (N_NODES + 255) / 256;
    const int edgeBlk = (N_EDGES + 255) / 256;
    const int gatherBlk = (N_NODES * 64 + 255) / 256;    // 1 wave/node, 4 waves/blk
    const int rowsPerBlock = (N_NODES + 255) / 256;

    // ---- CSR build + degrees
    zero_f4<<<(N_NODES / 4 + 255) / 256, 256, 0, stream>>>((float4*)deg, N_NODES / 4);
    count_deg<<<edgeBlk, 256, 0, stream>>>(dst, deg);
    deg_to_dis<<<nodeBlk, 256, 0, stream>>>(deg, dis);
    scan_chunk<<<NCHUNK, 256, 0, stream>>>(deg, row_start, chunk_sums);
    scan_tops<<<1, 256, 0, stream>>>(chunk_sums);
    scan_add<<<nodeBlk, 256, 0, stream>>>(row_start, chunk_sums);
    fill_adj<<<edgeBlk, 256, 0, stream>>>(src, dst, row_start, adj);
    // row_start[n] is now END of bucket n

    // ---- layer 1
    gemm_rowscale<<<gemmGrid, 256, 0, stream>>>(x, W1, dis, ht, N_NODES, IN_DIM);
    gather_relu<<<gatherBlk, 256, 0, stream>>>(ht, row_start, adj, dis, b1, s);

    // ---- layer 2 + BN1
    gemm_rowscale<<<gemmGrid, 256, 0, stream>>>(s, W2, dis, ht, N_NODES, HID);
    gather_relu<<<gatherBlk, 256, 0, stream>>>(ht, row_start, adj, dis, b2, s);
    zero_f4<<<1, 256, 0, stream>>>((float4*)stats, 2 * HID / 4);
    bn_stats<<<256, 256, 0, stream>>>(s, stats, rowsPerBlock);
    bn_apply<<<featBlk, 256, 0, stream>>>(s, stats, g1, be1);

    // ---- layer 3 + BN2
    gemm_rowscale<<<gemmGrid, 256, 0, stream>>>(s, W3, dis, ht, N_NODES, HID);
    gather_relu<<<gatherBlk, 256, 0, stream>>>(ht, row_start, adj, dis, b3, s);
    zero_f4<<<1, 256, 0, stream>>>((float4*)stats, 2 * HID / 4);
    bn_stats<<<256, 256, 0, stream>>>(s, stats, rowsPerBlock);
    bn_apply<<<featBlk, 256, 0, stream>>>(s, stats, g2, be2);

    // ---- pool + head
    zero_f4<<<(N_GRAPHS * HID / 4 + N_GRAPHS / 4 + 255) / 256, 256, 0, stream>>>(
        (float4*)pool, N_GRAPHS * HID / 4 + N_GRAPHS / 4);
    pool_accum<<<256, 256, 0, stream>>>(s, batch, pool, cnt, rowsPerBlock);
    final_head<<<N_GRAPHS, 256, 0, stream>>>(pool, cnt, Wf, bf, out);
}

// Round 9
// 917.666 us; speedup vs baseline: 9.4140x; 1.0929x over previous
//
#include <hip/hip_runtime.h>

#define N_NODES 50000
#define N_EDGES 800000
#define IN_DIM 128
#define HID 256
#define N_CLASSES 10
#define N_GRAPHS 64
#define BN_EPS 1e-5f
#define NCHUNK ((N_NODES + 255) / 256)   // 196

typedef _Float16 f16x8 __attribute__((ext_vector_type(8)));
typedef float f32x4 __attribute__((ext_vector_type(4)));

// ---------------------------------------------------------------- utilities
__global__ __launch_bounds__(256) void zero_f4(float4* __restrict__ p, int n4) {
    int i = blockIdx.x * blockDim.x + threadIdx.x;
    int stride = gridDim.x * blockDim.x;
    for (; i < n4; i += stride) p[i] = make_float4(0.f, 0.f, 0.f, 0.f);
}

// ---------------------------------------------------------------- CSR build
__global__ __launch_bounds__(256) void count_deg(const int* __restrict__ dst,
                                                 int* __restrict__ deg) {
    int e = blockIdx.x * blockDim.x + threadIdx.x;
    if (e < N_EDGES) atomicAdd(&deg[dst[e]], 1);
}

__global__ __launch_bounds__(256) void deg_to_dis(const int* __restrict__ deg,
                                                  float* __restrict__ dis) {
    int i = blockIdx.x * blockDim.x + threadIdx.x;
    if (i < N_NODES) dis[i] = rsqrtf(1.0f + (float)deg[i]);
}

// per-chunk exclusive scan; chunk totals out
__global__ __launch_bounds__(256) void scan_chunk(const int* __restrict__ deg,
                                                  int* __restrict__ row_start,
                                                  int* __restrict__ chunk_sums) {
    __shared__ int buf[256];
    int t = threadIdx.x;
    int i = blockIdx.x * 256 + t;
    int v = (i < N_NODES) ? deg[i] : 0;
    buf[t] = v;
    __syncthreads();
#pragma unroll
    for (int off = 1; off < 256; off <<= 1) {
        int tmp = (t >= off) ? buf[t - off] : 0;
        __syncthreads();
        buf[t] += tmp;
        __syncthreads();
    }
    if (i < N_NODES) row_start[i] = buf[t] - v;  // exclusive
    if (t == 255) chunk_sums[blockIdx.x] = buf[255];
}

// single-block exclusive scan of chunk sums
__global__ __launch_bounds__(256) void scan_tops(int* __restrict__ chunk_sums) {
    __shared__ int buf[256];
    int t = threadIdx.x;
    int v = (t < NCHUNK) ? chunk_sums[t] : 0;
    buf[t] = v;
    __syncthreads();
#pragma unroll
    for (int off = 1; off < 256; off <<= 1) {
        int tmp = (t >= off) ? buf[t - off] : 0;
        __syncthreads();
        buf[t] += tmp;
        __syncthreads();
    }
    if (t < NCHUNK) chunk_sums[t] = buf[t] - v;  // exclusive
}

__global__ __launch_bounds__(256) void scan_add(int* __restrict__ row_start,
                                                const int* __restrict__ chunk_sums) {
    int i = blockIdx.x * blockDim.x + threadIdx.x;
    if (i < N_NODES) row_start[i] += chunk_sums[i >> 8];
}

// fill buckets; destructively advances row_start -> end pointers
__global__ __launch_bounds__(256) void fill_adj(const int* __restrict__ src,
                                                const int* __restrict__ dst,
                                                int* __restrict__ row_start,
                                                int* __restrict__ adj) {
    int e = blockIdx.x * blockDim.x + threadIdx.x;
    if (e < N_EDGES) {
        int pos = atomicAdd(&row_start[dst[e]], 1);
        pos = min(pos, N_EDGES - 1);   // no-op when scan correct; fault guard
        adj[pos] = src[e];
    }
}

// ---------------------------------------------------------------- MFMA GEMM
// out[r][c] = (sum_k A[r][k] * W[k][c]) * dis[r]
// 64x64 tile, 4 waves; W slab transposed+f16-converted to LDS once per block,
// b-frags hoisted to registers (K compile-time so indices are static).
// Frag layout (verified m89/m92/m93 pattern): A,B^T both [row][k] in LDS,
// frag = 8 contiguous f16 at k=(lane>>4)*8; C/D col=lane&15,row=(lane>>4)*4+reg.
template<int K>
__global__ __launch_bounds__(256) void gemm_mfma(
    const float* __restrict__ A, const float* __restrict__ W,
    const float* __restrict__ dis, float* __restrict__ out, int M)
{
    __shared__ alignas(16) _Float16 Bs[64][264];  // [n][k], pad 264 (528B rows)
    __shared__ alignas(16) _Float16 As[64][40];   // [m][k] per 32-k step, 80B rows

    const int t    = threadIdx.x;
    const int wv   = t >> 6;
    const int lane = t & 63;
    const int row0 = blockIdx.x * 64;
    const int col0 = blockIdx.y * 64;

    // ---- stage whole B slab (K x 64 cols) as [n][k] f16
    {
        const int nc = (t & 7) * 8;
        for (int k = t >> 3; k < K; k += 32) {
            float4 w0 = *(const float4*)(W + (size_t)k * HID + col0 + nc);
            float4 w1 = *(const float4*)(W + (size_t)k * HID + col0 + nc + 4);
            Bs[nc + 0][k] = (_Float16)w0.x;
            Bs[nc + 1][k] = (_Float16)w0.y;
            Bs[nc + 2][k] = (_Float16)w0.z;
            Bs[nc + 3][k] = (_Float16)w0.w;
            Bs[nc + 4][k] = (_Float16)w1.x;
            Bs[nc + 5][k] = (_Float16)w1.y;
            Bs[nc + 6][k] = (_Float16)w1.z;
            Bs[nc + 7][k] = (_Float16)w1.w;
        }
    }
    __syncthreads();

    // ---- hoist b-fragments into registers (static indices via unroll)
    constexpr int NK = K / 32;
    f16x8 bfr[NK];
#pragma unroll
    for (int s = 0; s < NK; ++s)
        bfr[s] = *(const f16x8*)&Bs[wv * 16 + (lane & 15)][s * 32 + (lane >> 4) * 8];

    f32x4 acc[4] = {};

    const int ar = t >> 2;        // A tile row 0..63
    const int ac = (t & 3) * 8;   // k offset 0,8,16,24

#pragma unroll
    for (int s = 0; s < NK; ++s) {
        const int k0 = s * 32;
        float4 a0 = make_float4(0.f, 0.f, 0.f, 0.f);
        float4 a1 = make_float4(0.f, 0.f, 0.f, 0.f);
        int gr = row0 + ar;
        if (gr < M) {
            a0 = *(const float4*)(A + (size_t)gr * K + k0 + ac);
            a1 = *(const float4*)(A + (size_t)gr * K + k0 + ac + 4);
        }
        __syncthreads();   // prior iteration's frag reads complete
        f16x8 av;
        av[0] = (_Float16)a0.x; av[1] = (_Float16)a0.y;
        av[2] = (_Float16)a0.z; av[3] = (_Float16)a0.w;
        av[4] = (_Float16)a1.x; av[5] = (_Float16)a1.y;
        av[6] = (_Float16)a1.z; av[7] = (_Float16)a1.w;
        *(f16x8*)&As[ar][ac] = av;   // 16B aligned: 80*ar + 16*(t&3)
        __syncthreads();
#pragma unroll
        for (int m = 0; m < 4; ++m) {
            f16x8 af = *(const f16x8*)&As[m * 16 + (lane & 15)][(lane >> 4) * 8];
            acc[m] = __builtin_amdgcn_mfma_f32_16x16x32_f16(af, bfr[s], acc[m], 0, 0, 0);
        }
    }

    // ---- epilogue: C[row][col], row=(lane>>4)*4+i within each 16-row subtile
#pragma unroll
    for (int m = 0; m < 4; ++m) {
#pragma unroll
        for (int i = 0; i < 4; ++i) {
            int r = row0 + m * 16 + (lane >> 4) * 4 + i;
            if (r < M) {
                out[(size_t)r * HID + col0 + wv * 16 + (lane & 15)] = acc[m][i] * dis[r];
            }
        }
    }
}

// ---------------------------------------------------------------- gather
// One wave per node: s[n] = relu(dis[n]*(sum_{u in adj(n)} ht[u] + ht[n]) + b)
__global__ __launch_bounds__(256) void gather_relu(
    const float* __restrict__ ht, const int* __restrict__ row_end,
    const int* __restrict__ adj, const float* __restrict__ dis,
    const float* __restrict__ b, float* __restrict__ s)
{
    int wid  = (blockIdx.x * 256 + threadIdx.x) >> 6;  // node id
    int lane = threadIdx.x & 63;
    if (wid >= N_NODES) return;
    const int n = wid;
    const int c = lane * 4;
    int beg = (n == 0) ? 0 : row_end[n - 1];
    int end = row_end[n];

    float4 acc = *(const float4*)(ht + (size_t)n * HID + c);  // self loop

    int j = beg;
    while (j < end) {
        int m = end - j;
        if (m > 64) m = 64;
        int ul = adj[j + (lane < m ? lane : m - 1)];
        ul = min(ul, N_NODES - 1);   // no-op when adj valid; fault guard
        int k = 0;
        for (; k + 1 < m; k += 2) {
            int u0 = __shfl(ul, k);
            int u1 = __shfl(ul, k + 1);
            float4 v0 = *(const float4*)(ht + (size_t)u0 * HID + c);
            float4 v1 = *(const float4*)(ht + (size_t)u1 * HID + c);
            acc.x += v0.x + v1.x;
            acc.y += v0.y + v1.y;
            acc.z += v0.z + v1.z;
            acc.w += v0.w + v1.w;
        }
        if (k < m) {
            int u0 = __shfl(ul, k);
            float4 v0 = *(const float4*)(ht + (size_t)u0 * HID + c);
            acc.x += v0.x;
            acc.y += v0.y;
            acc.z += v0.z;
            acc.w += v0.w;
        }
        j += m;
    }

    float d = dis[n];
    float4 bv = ((const float4*)b)[lane];
    float4 o;
    o.x = fmaxf(fmaf(d, acc.x, bv.x), 0.f);
    o.y = fmaxf(fmaf(d, acc.y, bv.y), 0.f);
    o.z = fmaxf(fmaf(d, acc.z, bv.z), 0.f);
    o.w = fmaxf(fmaf(d, acc.w, bv.w), 0.f);
    *(float4*)(s + (size_t)n * HID + c) = o;
}

// ---------------------------------------------------------------- batch norm
__global__ __launch_bounds__(256) void bn_stats(
    const float* __restrict__ h, float* __restrict__ stats, int rows_per_block)
{
    int c  = threadIdx.x;
    int r0 = blockIdx.x * rows_per_block;
    int r1 = min(r0 + rows_per_block, N_NODES);
    if (r0 >= N_NODES) return;
    float sum = 0.f, sq = 0.f;
    for (int r = r0; r < r1; ++r) {
        float v = h[(size_t)r * HID + c];
        sum += v;
        sq  = fmaf(v, v, sq);
    }
    atomicAdd(&stats[c], sum);
    atomicAdd(&stats[HID + c], sq);
}

__global__ __launch_bounds__(256) void bn_apply(
    float* __restrict__ h, const float* __restrict__ stats,
    const float* __restrict__ g, const float* __restrict__ be)
{
    int idx = blockIdx.x * blockDim.x + threadIdx.x;
    const int total = N_NODES * (HID / 4);
    if (idx >= total) return;
    int c4 = idx & 63;
    const float invN = 1.0f / N_NODES;
    float4 sm = ((const float4*)stats)[c4];
    float4 sq = ((const float4*)(stats + HID))[c4];
    float4 gv = ((const float4*)g)[c4];
    float4 bv = ((const float4*)be)[c4];
    float4 v  = ((float4*)h)[idx];
    float4 o;
    float mu, var, sc;
    mu = sm.x * invN; var = sq.x * invN - mu * mu; sc = rsqrtf(var + BN_EPS) * gv.x;
    o.x = (v.x - mu) * sc + bv.x;
    mu = sm.y * invN; var = sq.y * invN - mu * mu; sc = rsqrtf(var + BN_EPS) * gv.y;
    o.y = (v.y - mu) * sc + bv.y;
    mu = sm.z * invN; var = sq.z * invN - mu * mu; sc = rsqrtf(var + BN_EPS) * gv.z;
    o.z = (v.z - mu) * sc + bv.z;
    mu = sm.w * invN; var = sq.w * invN - mu * mu; sc = rsqrtf(var + BN_EPS) * gv.w;
    o.w = (v.w - mu) * sc + bv.w;
    ((float4*)h)[idx] = o;
}

// ---------------------------------------------------------------- pooling
__global__ __launch_bounds__(256) void pool_accum(
    const float* __restrict__ h, const int* __restrict__ batch,
    float* __restrict__ pool, float* __restrict__ cnt, int rows_per_block)
{
    int c  = threadIdx.x;
    int r0 = blockIdx.x * rows_per_block;
    int r1 = min(r0 + rows_per_block, N_NODES);
    if (r0 >= N_NODES) return;
    float acc = 0.f;
    int curg = batch[r0];
    for (int r = r0; r < r1; ++r) {
        int gidx = batch[r];
        if (gidx != curg) {
            atomicAdd(&pool[(size_t)curg * HID + c], acc);
            acc = 0.f;
            curg = gidx;
        }
        acc += h[(size_t)r * HID + c];
    }
    atomicAdd(&pool[(size_t)curg * HID + c], acc);
    if (c == 0) {
        int cacc = 0;
        int cg = batch[r0];
        for (int r = r0; r < r1; ++r) {
            int gidx = batch[r];
            if (gidx != cg) { atomicAdd(&cnt[cg], (float)cacc); cacc = 0; cg = gidx; }
            cacc++;
        }
        atomicAdd(&cnt[cg], (float)cacc);
    }
}

__global__ __launch_bounds__(256) void final_head(
    const float* __restrict__ pool, const float* __restrict__ cnt,
    const float* __restrict__ Wf, const float* __restrict__ bf,
    float* __restrict__ out)
{
    __shared__ float p[HID];
    int g = blockIdx.x;
    int c = threadIdx.x;
    float inv = 1.0f / fmaxf(cnt[g], 1.0f);
    p[c] = pool[(size_t)g * HID + c] * inv;
    __syncthreads();
    if (c < N_CLASSES) {
        float acc = bf[c];
        for (int k = 0; k < HID; ++k) acc = fmaf(p[k], Wf[k * N_CLASSES + c], acc);
        out[g * N_CLASSES + c] = acc;
    }
}

// ---------------------------------------------------------------- launch
extern "C" void kernel_launch(void* const* d_in, const int* in_sizes, int n_in,
                              void* d_out, int out_size, void* d_ws, size_t ws_size,
                              hipStream_t stream) {
    const float* x   = (const float*)d_in[0];
    const int* eidx  = (const int*)d_in[1];
    const int* batch = (const int*)d_in[2];
    const float* W1  = (const float*)d_in[3];
    const float* b1  = (const float*)d_in[4];
    const float* W2  = (const float*)d_in[5];
    const float* b2  = (const float*)d_in[6];
    const float* W3  = (const float*)d_in[7];
    const float* b3  = (const float*)d_in[8];
    const float* g1  = (const float*)d_in[9];
    const float* be1 = (const float*)d_in[10];
    const float* g2  = (const float*)d_in[11];
    const float* be2 = (const float*)d_in[12];
    const float* Wf  = (const float*)d_in[13];
    const float* bf  = (const float*)d_in[14];
    float* out = (float*)d_out;

    const int* src = eidx;
    const int* dst = eidx + N_EDGES;

    // workspace layout (~106.3 MB, proven in round 8)
    float* ht        = (float*)d_ws;                     // 12.8M f
    float* s         = ht + (size_t)N_NODES * HID;       // 12.8M f
    float* dis       = s + (size_t)N_NODES * HID;        // 50000 f
    float* stats     = dis + N_NODES;                    // 512 f
    float* pool      = stats + 2 * HID;                  // 16384 f
    float* cnt       = pool + (size_t)N_GRAPHS * HID;    // 64 f
    int* deg         = (int*)(cnt + N_GRAPHS);           // 50000 i
    int* row_start   = deg + N_NODES;                    // 50000 i
    int* chunk_sums  = row_start + N_NODES;              // 256 i
    int* adj         = chunk_sums + 256;                 // 800000 i

    const int feat4   = N_NODES * (HID / 4);
    const int featBlk = (feat4 + 255) / 256;
    const int mTiles  = (N_NODES + 63) / 64;             // 782
    dim3 gemmGrid(mTiles, HID / 64);                     // 782 x 4
    const int nodeBlk = (N_NODES + 255) / 256;
    const int edgeBlk = (N_EDGES + 255) / 256;
    const int gatherBlk = (N_NODES * 64 + 255) / 256;    // 1 wave/node
    const int rowsPerBlock = (N_NODES + 255) / 256;

    // ---- CSR build + degrees
    zero_f4<<<(N_NODES / 4 + 255) / 256, 256, 0, stream>>>((float4*)deg, N_NODES / 4);
    count_deg<<<edgeBlk, 256, 0, stream>>>(dst, deg);
    deg_to_dis<<<nodeBlk, 256, 0, stream>>>(deg, dis);
    scan_chunk<<<NCHUNK, 256, 0, stream>>>(deg, row_start, chunk_sums);
    scan_tops<<<1, 256, 0, stream>>>(chunk_sums);
    scan_add<<<nodeBlk, 256, 0, stream>>>(row_start, chunk_sums);
    fill_adj<<<edgeBlk, 256, 0, stream>>>(src, dst, row_start, adj);
    // row_start[n] is now END of bucket n

    // ---- layer 1
    gemm_mfma<IN_DIM><<<gemmGrid, 256, 0, stream>>>(x, W1, dis, ht, N_NODES);
    gather_relu<<<gatherBlk, 256, 0, stream>>>(ht, row_start, adj, dis, b1, s);

    // ---- layer 2 + BN1
    gemm_mfma<HID><<<gemmGrid, 256, 0, stream>>>(s, W2, dis, ht, N_NODES);
    gather_relu<<<gatherBlk, 256, 0, stream>>>(ht, row_start, adj, dis, b2, s);
    zero_f4<<<1, 256, 0, stream>>>((float4*)stats, 2 * HID / 4);
    bn_stats<<<256, 256, 0, stream>>>(s, stats, rowsPerBlock);
    bn_apply<<<featBlk, 256, 0, stream>>>(s, stats, g1, be1);

    // ---- layer 3 + BN2
    gemm_mfma<HID><<<gemmGrid, 256, 0, stream>>>(s, W3, dis, ht, N_NODES);
    gather_relu<<<gatherBlk, 256, 0, stream>>>(ht, row_start, adj, dis, b3, s);
    zero_f4<<<1, 256, 0, stream>>>((float4*)stats, 2 * HID / 4);
    bn_stats<<<256, 256, 0, stream>>>(s, stats, rowsPerBlock);
    bn_apply<<<featBlk, 256, 0, stream>>>(s, stats, g2, be2);

    // ---- pool + head
    zero_f4<<<(N_GRAPHS * HID / 4 + N_GRAPHS / 4 + 255) / 256, 256, 0, stream>>>(
        (float4*)pool, N_GRAPHS * HID / 4 + N_GRAPHS / 4);
    pool_accum<<<256, 256, 0, stream>>>(s, batch, pool, cnt, rowsPerBlock);
    final_head<<<N_GRAPHS, 256, 0, stream>>>(pool, cnt, Wf, bf, out);
}

// Round 10
// 720.315 us; speedup vs baseline: 11.9932x; 1.2740x over previous
//
#include <hip/hip_runtime.h>

#define N_NODES 50000
#define N_EDGES 800000
#define IN_DIM 128
#define HID 256
#define N_CLASSES 10
#define N_GRAPHS 64
#define BN_EPS 1e-5f
#define NCHUNK ((N_NODES + 255) / 256)   // 196

typedef _Float16 f16x8 __attribute__((ext_vector_type(8)));
typedef _Float16 f16x4 __attribute__((ext_vector_type(4)));
typedef float f32x4 __attribute__((ext_vector_type(4)));

// ---------------------------------------------------------------- utilities
__global__ __launch_bounds__(256) void zero_f4(float4* __restrict__ p, int n4) {
    int i = blockIdx.x * blockDim.x + threadIdx.x;
    int stride = gridDim.x * blockDim.x;
    for (; i < n4; i += stride) p[i] = make_float4(0.f, 0.f, 0.f, 0.f);
}

// ---------------------------------------------------------------- CSR build
__global__ __launch_bounds__(256) void count_deg(const int* __restrict__ dst,
                                                 int* __restrict__ deg) {
    int e = blockIdx.x * blockDim.x + threadIdx.x;
    if (e < N_EDGES) atomicAdd(&deg[dst[e]], 1);
}

__global__ __launch_bounds__(256) void deg_to_dis(const int* __restrict__ deg,
                                                  float* __restrict__ dis) {
    int i = blockIdx.x * blockDim.x + threadIdx.x;
    if (i < N_NODES) dis[i] = rsqrtf(1.0f + (float)deg[i]);
}

// per-chunk exclusive scan; chunk totals out
__global__ __launch_bounds__(256) void scan_chunk(const int* __restrict__ deg,
                                                  int* __restrict__ row_start,
                                                  int* __restrict__ chunk_sums) {
    __shared__ int buf[256];
    int t = threadIdx.x;
    int i = blockIdx.x * 256 + t;
    int v = (i < N_NODES) ? deg[i] : 0;
    buf[t] = v;
    __syncthreads();
#pragma unroll
    for (int off = 1; off < 256; off <<= 1) {
        int tmp = (t >= off) ? buf[t - off] : 0;
        __syncthreads();
        buf[t] += tmp;
        __syncthreads();
    }
    if (i < N_NODES) row_start[i] = buf[t] - v;  // exclusive
    if (t == 255) chunk_sums[blockIdx.x] = buf[255];
}

// single-block exclusive scan of chunk sums
__global__ __launch_bounds__(256) void scan_tops(int* __restrict__ chunk_sums) {
    __shared__ int buf[256];
    int t = threadIdx.x;
    int v = (t < NCHUNK) ? chunk_sums[t] : 0;
    buf[t] = v;
    __syncthreads();
#pragma unroll
    for (int off = 1; off < 256; off <<= 1) {
        int tmp = (t >= off) ? buf[t - off] : 0;
        __syncthreads();
        buf[t] += tmp;
        __syncthreads();
    }
    if (t < NCHUNK) chunk_sums[t] = buf[t] - v;  // exclusive
}

__global__ __launch_bounds__(256) void scan_add(int* __restrict__ row_start,
                                                const int* __restrict__ chunk_sums) {
    int i = blockIdx.x * blockDim.x + threadIdx.x;
    if (i < N_NODES) row_start[i] += chunk_sums[i >> 8];
}

// fill buckets; destructively advances row_start -> end pointers
__global__ __launch_bounds__(256) void fill_adj(const int* __restrict__ src,
                                                const int* __restrict__ dst,
                                                int* __restrict__ row_start,
                                                int* __restrict__ adj) {
    int e = blockIdx.x * blockDim.x + threadIdx.x;
    if (e < N_EDGES) {
        int pos = atomicAdd(&row_start[dst[e]], 1);
        pos = min(pos, N_EDGES - 1);   // no-op when scan correct; fault guard
        adj[pos] = src[e];
    }
}

// ---------------------------------------------------------------- MFMA GEMM
// ht[r][c] = f16( (sum_k A[r][k] * W[k][c]) * dis[r] )
// 64x64 tile, 4 waves; W slab transposed+f16-converted to LDS once per block,
// b-frags hoisted to registers (K compile-time so indices are static).
template<int K>
__global__ __launch_bounds__(256) void gemm_mfma(
    const float* __restrict__ A, const float* __restrict__ W,
    const float* __restrict__ dis, _Float16* __restrict__ out, int M)
{
    __shared__ alignas(16) _Float16 Bs[64][264];  // [n][k], pad 264
    __shared__ alignas(16) _Float16 As[64][40];   // [m][k] per 32-k step

    const int t    = threadIdx.x;
    const int wv   = t >> 6;
    const int lane = t & 63;
    const int row0 = blockIdx.x * 64;
    const int col0 = blockIdx.y * 64;

    // ---- stage whole B slab (K x 64 cols) as [n][k] f16
    {
        const int nc = (t & 7) * 8;
        for (int k = t >> 3; k < K; k += 32) {
            float4 w0 = *(const float4*)(W + (size_t)k * HID + col0 + nc);
            float4 w1 = *(const float4*)(W + (size_t)k * HID + col0 + nc + 4);
            Bs[nc + 0][k] = (_Float16)w0.x;
            Bs[nc + 1][k] = (_Float16)w0.y;
            Bs[nc + 2][k] = (_Float16)w0.z;
            Bs[nc + 3][k] = (_Float16)w0.w;
            Bs[nc + 4][k] = (_Float16)w1.x;
            Bs[nc + 5][k] = (_Float16)w1.y;
            Bs[nc + 6][k] = (_Float16)w1.z;
            Bs[nc + 7][k] = (_Float16)w1.w;
        }
    }
    __syncthreads();

    // ---- hoist b-fragments into registers (static indices via unroll)
    constexpr int NK = K / 32;
    f16x8 bfr[NK];
#pragma unroll
    for (int s = 0; s < NK; ++s)
        bfr[s] = *(const f16x8*)&Bs[wv * 16 + (lane & 15)][s * 32 + (lane >> 4) * 8];

    f32x4 acc[4] = {};

    const int ar = t >> 2;        // A tile row 0..63
    const int ac = (t & 3) * 8;   // k offset 0,8,16,24

#pragma unroll
    for (int s = 0; s < NK; ++s) {
        const int k0 = s * 32;
        float4 a0 = make_float4(0.f, 0.f, 0.f, 0.f);
        float4 a1 = make_float4(0.f, 0.f, 0.f, 0.f);
        int gr = row0 + ar;
        if (gr < M) {
            a0 = *(const float4*)(A + (size_t)gr * K + k0 + ac);
            a1 = *(const float4*)(A + (size_t)gr * K + k0 + ac + 4);
        }
        __syncthreads();   // prior iteration's frag reads complete
        f16x8 av;
        av[0] = (_Float16)a0.x; av[1] = (_Float16)a0.y;
        av[2] = (_Float16)a0.z; av[3] = (_Float16)a0.w;
        av[4] = (_Float16)a1.x; av[5] = (_Float16)a1.y;
        av[6] = (_Float16)a1.z; av[7] = (_Float16)a1.w;
        *(f16x8*)&As[ar][ac] = av;
        __syncthreads();
#pragma unroll
        for (int m = 0; m < 4; ++m) {
            f16x8 af = *(const f16x8*)&As[m * 16 + (lane & 15)][(lane >> 4) * 8];
            acc[m] = __builtin_amdgcn_mfma_f32_16x16x32_f16(af, bfr[s], acc[m], 0, 0, 0);
        }
    }

    // ---- epilogue: C col=lane&15 (+wv*16), row=(lane>>4)*4+i per 16-row subtile
#pragma unroll
    for (int m = 0; m < 4; ++m) {
#pragma unroll
        for (int i = 0; i < 4; ++i) {
            int r = row0 + m * 16 + (lane >> 4) * 4 + i;
            if (r < M) {
                out[(size_t)r * HID + col0 + wv * 16 + (lane & 15)] =
                    (_Float16)(acc[m][i] * dis[r]);
            }
        }
    }
}

// ---------------------------------------------------------------- gather
// One wave per node: s[n] = relu(dis[n]*(sum_{u in adj(n)} ht[u] + ht[n]) + b)
// ht is fp16 (512B rows); accumulate fp32; s stays fp32.
__global__ __launch_bounds__(256) void gather_relu(
    const _Float16* __restrict__ ht, const int* __restrict__ row_end,
    const int* __restrict__ adj, const float* __restrict__ dis,
    const float* __restrict__ b, float* __restrict__ s)
{
    int wid  = (blockIdx.x * 256 + threadIdx.x) >> 6;  // node id
    int lane = threadIdx.x & 63;
    if (wid >= N_NODES) return;
    const int n = wid;
    const int c = lane * 4;
    int beg = (n == 0) ? 0 : row_end[n - 1];
    int end = row_end[n];

    f16x4 sv = *(const f16x4*)(ht + (size_t)n * HID + c);  // self loop
    float4 acc = make_float4((float)sv[0], (float)sv[1], (float)sv[2], (float)sv[3]);

    int j = beg;
    while (j < end) {
        int m = end - j;
        if (m > 64) m = 64;
        int ul = adj[j + (lane < m ? lane : m - 1)];
        ul = min(ul, N_NODES - 1);   // no-op when adj valid; fault guard
        int k = 0;
        for (; k + 1 < m; k += 2) {
            int u0 = __shfl(ul, k);
            int u1 = __shfl(ul, k + 1);
            f16x4 v0 = *(const f16x4*)(ht + (size_t)u0 * HID + c);
            f16x4 v1 = *(const f16x4*)(ht + (size_t)u1 * HID + c);
            acc.x += (float)v0[0] + (float)v1[0];
            acc.y += (float)v0[1] + (float)v1[1];
            acc.z += (float)v0[2] + (float)v1[2];
            acc.w += (float)v0[3] + (float)v1[3];
        }
        if (k < m) {
            int u0 = __shfl(ul, k);
            f16x4 v0 = *(const f16x4*)(ht + (size_t)u0 * HID + c);
            acc.x += (float)v0[0];
            acc.y += (float)v0[1];
            acc.z += (float)v0[2];
            acc.w += (float)v0[3];
        }
        j += m;
    }

    float d = dis[n];
    float4 bv = ((const float4*)b)[lane];
    float4 o;
    o.x = fmaxf(fmaf(d, acc.x, bv.x), 0.f);
    o.y = fmaxf(fmaf(d, acc.y, bv.y), 0.f);
    o.z = fmaxf(fmaf(d, acc.z, bv.z), 0.f);
    o.w = fmaxf(fmaf(d, acc.w, bv.w), 0.f);
    *(float4*)(s + (size_t)n * HID + c) = o;
}

// ---------------------------------------------------------------- batch norm
__global__ __launch_bounds__(256) void bn_stats(
    const float* __restrict__ h, float* __restrict__ stats, int rows_per_block)
{
    int c  = threadIdx.x;
    int r0 = blockIdx.x * rows_per_block;
    int r1 = min(r0 + rows_per_block, N_NODES);
    if (r0 >= N_NODES) return;
    float sum = 0.f, sq = 0.f;
    for (int r = r0; r < r1; ++r) {
        float v = h[(size_t)r * HID + c];
        sum += v;
        sq  = fmaf(v, v, sq);
    }
    atomicAdd(&stats[c], sum);
    atomicAdd(&stats[HID + c], sq);
}

__global__ __launch_bounds__(256) void bn_apply(
    float* __restrict__ h, const float* __restrict__ stats,
    const float* __restrict__ g, const float* __restrict__ be)
{
    int idx = blockIdx.x * blockDim.x + threadIdx.x;
    const int total = N_NODES * (HID / 4);
    if (idx >= total) return;
    int c4 = idx & 63;
    const float invN = 1.0f / N_NODES;
    float4 sm = ((const float4*)stats)[c4];
    float4 sq = ((const float4*)(stats + HID))[c4];
    float4 gv = ((const float4*)g)[c4];
    float4 bv = ((const float4*)be)[c4];
    float4 v  = ((float4*)h)[idx];
    float4 o;
    float mu, var, sc;
    mu = sm.x * invN; var = sq.x * invN - mu * mu; sc = rsqrtf(var + BN_EPS) * gv.x;
    o.x = (v.x - mu) * sc + bv.x;
    mu = sm.y * invN; var = sq.y * invN - mu * mu; sc = rsqrtf(var + BN_EPS) * gv.y;
    o.y = (v.y - mu) * sc + bv.y;
    mu = sm.z * invN; var = sq.z * invN - mu * mu; sc = rsqrtf(var + BN_EPS) * gv.z;
    o.z = (v.z - mu) * sc + bv.z;
    mu = sm.w * invN; var = sq.w * invN - mu * mu; sc = rsqrtf(var + BN_EPS) * gv.w;
    o.w = (v.w - mu) * sc + bv.w;
    ((float4*)h)[idx] = o;
}

// ---------------------------------------------------------------- pooling
__global__ __launch_bounds__(256) void pool_accum(
    const float* __restrict__ h, const int* __restrict__ batch,
    float* __restrict__ pool, float* __restrict__ cnt, int rows_per_block)
{
    int c  = threadIdx.x;
    int r0 = blockIdx.x * rows_per_block;
    int r1 = min(r0 + rows_per_block, N_NODES);
    if (r0 >= N_NODES) return;
    float acc = 0.f;
    int curg = batch[r0];
    for (int r = r0; r < r1; ++r) {
        int gidx = batch[r];
        if (gidx != curg) {
            atomicAdd(&pool[(size_t)curg * HID + c], acc);
            acc = 0.f;
            curg = gidx;
        }
        acc += h[(size_t)r * HID + c];
    }
    atomicAdd(&pool[(size_t)curg * HID + c], acc);
    if (c == 0) {
        int cacc = 0;
        int cg = batch[r0];
        for (int r = r0; r < r1; ++r) {
            int gidx = batch[r];
            if (gidx != cg) { atomicAdd(&cnt[cg], (float)cacc); cacc = 0; cg = gidx; }
            cacc++;
        }
        atomicAdd(&cnt[cg], (float)cacc);
    }
}

__global__ __launch_bounds__(256) void final_head(
    const float* __restrict__ pool, const float* __restrict__ cnt,
    const float* __restrict__ Wf, const float* __restrict__ bf,
    float* __restrict__ out)
{
    __shared__ float p[HID];
    int g = blockIdx.x;
    int c = threadIdx.x;
    float inv = 1.0f / fmaxf(cnt[g], 1.0f);
    p[c] = pool[(size_t)g * HID + c] * inv;
    __syncthreads();
    if (c < N_CLASSES) {
        float acc = bf[c];
        for (int k = 0; k < HID; ++k) acc = fmaf(p[k], Wf[k * N_CLASSES + c], acc);
        out[g * N_CLASSES + c] = acc;
    }
}

// ---------------------------------------------------------------- launch
extern "C" void kernel_launch(void* const* d_in, const int* in_sizes, int n_in,
                              void* d_out, int out_size, void* d_ws, size_t ws_size,
                              hipStream_t stream) {
    const float* x   = (const float*)d_in[0];
    const int* eidx  = (const int*)d_in[1];
    const int* batch = (const int*)d_in[2];
    const float* W1  = (const float*)d_in[3];
    const float* b1  = (const float*)d_in[4];
    const float* W2  = (const float*)d_in[5];
    const float* b2  = (const float*)d_in[6];
    const float* W3  = (const float*)d_in[7];
    const float* b3  = (const float*)d_in[8];
    const float* g1  = (const float*)d_in[9];
    const float* be1 = (const float*)d_in[10];
    const float* g2  = (const float*)d_in[11];
    const float* be2 = (const float*)d_in[12];
    const float* Wf  = (const float*)d_in[13];
    const float* bf  = (const float*)d_in[14];
    float* out = (float*)d_out;

    const int* src = eidx;
    const int* dst = eidx + N_EDGES;

    // workspace layout (~80.7 MB)
    _Float16* ht     = (_Float16*)d_ws;                      // 12.8M f16
    float* s         = (float*)(ht + (size_t)N_NODES * HID); // 12.8M f
    float* dis       = s + (size_t)N_NODES * HID;            // 50000 f
    float* stats     = dis + N_NODES;                        // 512 f
    float* pool      = stats + 2 * HID;                      // 16384 f
    float* cnt       = pool + (size_t)N_GRAPHS * HID;        // 64 f
    int* deg         = (int*)(cnt + N_GRAPHS);               // 50000 i
    int* row_start   = deg + N_NODES;                        // 50000 i
    int* chunk_sums  = row_start + N_NODES;                  // 256 i
    int* adj         = chunk_sums + 256;                     // 800000 i

    const int feat4   = N_NODES * (HID / 4);
    const int featBlk = (feat4 + 255) / 256;
    const int mTiles  = (N_NODES + 63) / 64;             // 782
    dim3 gemmGrid(mTiles, HID / 64);                     // 782 x 4
    const int nodeBlk = (N_NODES + 255) / 256;
    const int edgeBlk = (N_EDGES + 255) / 256;
    const int gatherBlk = (N_NODES * 64 + 255) / 256;    // 1 wave/node
    const int rowsPerBlock = (N_NODES + 255) / 256;

    // ---- CSR build + degrees
    zero_f4<<<(N_NODES / 4 + 255) / 256, 256, 0, stream>>>((float4*)deg, N_NODES / 4);
    count_deg<<<edgeBlk, 256, 0, stream>>>(dst, deg);
    deg_to_dis<<<nodeBlk, 256, 0, stream>>>(deg, dis);
    scan_chunk<<<NCHUNK, 256, 0, stream>>>(deg, row_start, chunk_sums);
    scan_tops<<<1, 256, 0, stream>>>(chunk_sums);
    scan_add<<<nodeBlk, 256, 0, stream>>>(row_start, chunk_sums);
    fill_adj<<<edgeBlk, 256, 0, stream>>>(src, dst, row_start, adj);
    // row_start[n] is now END of bucket n

    // ---- layer 1
    gemm_mfma<IN_DIM><<<gemmGrid, 256, 0, stream>>>(x, W1, dis, ht, N_NODES);
    gather_relu<<<gatherBlk, 256, 0, stream>>>(ht, row_start, adj, dis, b1, s);

    // ---- layer 2 + BN1
    gemm_mfma<HID><<<gemmGrid, 256, 0, stream>>>(s, W2, dis, ht, N_NODES);
    gather_relu<<<gatherBlk, 256, 0, stream>>>(ht, row_start, adj, dis, b2, s);
    zero_f4<<<1, 256, 0, stream>>>((float4*)stats, 2 * HID / 4);
    bn_stats<<<256, 256, 0, stream>>>(s, stats, rowsPerBlock);
    bn_apply<<<featBlk, 256, 0, stream>>>(s, stats, g1, be1);

    // ---- layer 3 + BN2
    gemm_mfma<HID><<<gemmGrid, 256, 0, stream>>>(s, W3, dis, ht, N_NODES);
    gather_relu<<<gatherBlk, 256, 0, stream>>>(ht, row_start, adj, dis, b3, s);
    zero_f4<<<1, 256, 0, stream>>>((float4*)stats, 2 * HID / 4);
    bn_stats<<<256, 256, 0, stream>>>(s, stats, rowsPerBlock);
    bn_apply<<<featBlk, 256, 0, stream>>>(s, stats, g2, be2);

    // ---- pool + head
    zero_f4<<<(N_GRAPHS * HID / 4 + N_GRAPHS / 4 + 255) / 256, 256, 0, stream>>>(
        (float4*)pool, N_GRAPHS * HID / 4 + N_GRAPHS / 4);
    pool_accum<<<256, 256, 0, stream>>>(s, batch, pool, cnt, rowsPerBlock);
    final_head<<<N_GRAPHS, 256, 0, stream>>>(pool, cnt, Wf, bf, out);
}

// Round 14
// 675.236 us; speedup vs baseline: 12.7939x; 1.0668x over previous
//
#include <hip/hip_runtime.h>

#define N_NODES 50000
#define N_EDGES 800000
#define IN_DIM 128
#define HID 256
#define N_CLASSES 10
#define N_GRAPHS 64
#define BN_EPS 1e-5f
#define NCHUNK ((N_NODES + 255) / 256)   // 196

typedef _Float16 f16x8 __attribute__((ext_vector_type(8)));
typedef _Float16 f16x4 __attribute__((ext_vector_type(4)));
typedef float f32x4 __attribute__((ext_vector_type(4)));

// ---------------------------------------------------------------- utilities
__global__ __launch_bounds__(256) void zero_f4(float4* __restrict__ p, int n4) {
    int i = blockIdx.x * blockDim.x + threadIdx.x;
    int stride = gridDim.x * blockDim.x;
    for (; i < n4; i += stride) p[i] = make_float4(0.f, 0.f, 0.f, 0.f);
}

// ---------------------------------------------------------------- CSR build
__global__ __launch_bounds__(256) void count_deg(const int* __restrict__ dst,
                                                 int* __restrict__ deg) {
    int e = blockIdx.x * blockDim.x + threadIdx.x;
    if (e < N_EDGES) atomicAdd(&deg[dst[e]], 1);
}

// per-chunk exclusive scan; chunk totals out; also emits dis = rsqrt(1+deg)
__global__ __launch_bounds__(256) void scan_chunk(const int* __restrict__ deg,
                                                  int* __restrict__ row_start,
                                                  int* __restrict__ chunk_sums,
                                                  float* __restrict__ dis) {
    __shared__ int buf[256];
    int t = threadIdx.x;
    int i = blockIdx.x * 256 + t;
    int v = (i < N_NODES) ? deg[i] : 0;
    buf[t] = v;
    __syncthreads();
#pragma unroll
    for (int off = 1; off < 256; off <<= 1) {
        int tmp = (t >= off) ? buf[t - off] : 0;
        __syncthreads();
        buf[t] += tmp;
        __syncthreads();
    }
    if (i < N_NODES) {
        row_start[i] = buf[t] - v;  // exclusive
        dis[i] = rsqrtf(1.0f + (float)v);
    }
    if (t == 255) chunk_sums[blockIdx.x] = buf[255];
}

// single-block exclusive scan of chunk sums
__global__ __launch_bounds__(256) void scan_tops(int* __restrict__ chunk_sums) {
    __shared__ int buf[256];
    int t = threadIdx.x;
    int v = (t < NCHUNK) ? chunk_sums[t] : 0;
    buf[t] = v;
    __syncthreads();
#pragma unroll
    for (int off = 1; off < 256; off <<= 1) {
        int tmp = (t >= off) ? buf[t - off] : 0;
        __syncthreads();
        buf[t] += tmp;
        __syncthreads();
    }
    if (t < NCHUNK) chunk_sums[t] = buf[t] - v;  // exclusive
}

__global__ __launch_bounds__(256) void scan_add(int* __restrict__ row_start,
                                                const int* __restrict__ chunk_sums) {
    int i = blockIdx.x * blockDim.x + threadIdx.x;
    if (i < N_NODES) row_start[i] += chunk_sums[i >> 8];
}

// fill buckets; destructively advances row_start -> end pointers
__global__ __launch_bounds__(256) void fill_adj(const int* __restrict__ src,
                                                const int* __restrict__ dst,
                                                int* __restrict__ row_start,
                                                int* __restrict__ adj) {
    int e = blockIdx.x * blockDim.x + threadIdx.x;
    if (e < N_EDGES) {
        int pos = atomicAdd(&row_start[dst[e]], 1);
        pos = min(pos, N_EDGES - 1);   // no-op when scan correct; fault guard
        adj[pos] = src[e];
    }
}

// ---------------------------------------------------------------- MFMA GEMM
// ht[r][c] = f16( (sum_k A'[r][k] * W[k][c]) * dis[r] )
// BN=true: A' = (A - mu[k])*rsqrt(var[k]+eps)*g[k] + be[k], from stats, fused
// into the f32->f16 A-staging (exact BN1-apply fold).
template<int K, bool BN>
__global__ __launch_bounds__(256) void gemm_mfma(
    const float* __restrict__ A, const float* __restrict__ W,
    const float* __restrict__ dis, const float* __restrict__ stats,
    const float* __restrict__ g, const float* __restrict__ be,
    _Float16* __restrict__ out, int M)
{
    __shared__ alignas(16) _Float16 Bs[64][264];  // [n][k], pad 264
    __shared__ alignas(16) _Float16 As[64][40];   // [m][k] per 32-k step

    const int t    = threadIdx.x;
    const int wv   = t >> 6;
    const int lane = t & 63;
    const int row0 = blockIdx.x * 64;
    const int col0 = blockIdx.y * 64;

    // ---- stage whole B slab (K x 64 cols) as [n][k] f16
    {
        const int nc = (t & 7) * 8;
        for (int k = t >> 3; k < K; k += 32) {
            float4 w0 = *(const float4*)(W + (size_t)k * HID + col0 + nc);
            float4 w1 = *(const float4*)(W + (size_t)k * HID + col0 + nc + 4);
            Bs[nc + 0][k] = (_Float16)w0.x;
            Bs[nc + 1][k] = (_Float16)w0.y;
            Bs[nc + 2][k] = (_Float16)w0.z;
            Bs[nc + 3][k] = (_Float16)w0.w;
            Bs[nc + 4][k] = (_Float16)w1.x;
            Bs[nc + 5][k] = (_Float16)w1.y;
            Bs[nc + 6][k] = (_Float16)w1.z;
            Bs[nc + 7][k] = (_Float16)w1.w;
        }
    }
    __syncthreads();

    // ---- hoist b-fragments into registers (static indices via unroll)
    constexpr int NK = K / 32;
    f16x8 bfr[NK];
#pragma unroll
    for (int s = 0; s < NK; ++s)
        bfr[s] = *(const f16x8*)&Bs[wv * 16 + (lane & 15)][s * 32 + (lane >> 4) * 8];

    f32x4 acc[4] = {};

    const int ar = t >> 2;        // A tile row 0..63
    const int ac = (t & 3) * 8;   // k offset 0,8,16,24
    const float invN = 1.0f / N_NODES;

#pragma unroll
    for (int s = 0; s < NK; ++s) {
        const int k0 = s * 32;
        float4 a0 = make_float4(0.f, 0.f, 0.f, 0.f);
        float4 a1 = make_float4(0.f, 0.f, 0.f, 0.f);
        int gr = row0 + ar;
        if (gr < M) {
            a0 = *(const float4*)(A + (size_t)gr * K + k0 + ac);
            a1 = *(const float4*)(A + (size_t)gr * K + k0 + ac + 4);
        }
        if constexpr (BN) {
            const int kc = k0 + ac;
            float4 sm0 = *(const float4*)(stats + kc);
            float4 sm1 = *(const float4*)(stats + kc + 4);
            float4 sq0 = *(const float4*)(stats + HID + kc);
            float4 sq1 = *(const float4*)(stats + HID + kc + 4);
            float4 gv0 = *(const float4*)(g + kc);
            float4 gv1 = *(const float4*)(g + kc + 4);
            float4 bv0 = *(const float4*)(be + kc);
            float4 bv1 = *(const float4*)(be + kc + 4);
            float mu, var, sc;
            mu = sm0.x * invN; var = sq0.x * invN - mu * mu;
            sc = rsqrtf(var + BN_EPS) * gv0.x; a0.x = (a0.x - mu) * sc + bv0.x;
            mu = sm0.y * invN; var = sq0.y * invN - mu * mu;
            sc = rsqrtf(var + BN_EPS) * gv0.y; a0.y = (a0.y - mu) * sc + bv0.y;
            mu = sm0.z * invN; var = sq0.z * invN - mu * mu;
            sc = rsqrtf(var + BN_EPS) * gv0.z; a0.z = (a0.z - mu) * sc + bv0.z;
            mu = sm0.w * invN; var = sq0.w * invN - mu * mu;
            sc = rsqrtf(var + BN_EPS) * gv0.w; a0.w = (a0.w - mu) * sc + bv0.w;
            mu = sm1.x * invN; var = sq1.x * invN - mu * mu;
            sc = rsqrtf(var + BN_EPS) * gv1.x; a1.x = (a1.x - mu) * sc + bv1.x;
            mu = sm1.y * invN; var = sq1.y * invN - mu * mu;
            sc = rsqrtf(var + BN_EPS) * gv1.y; a1.y = (a1.y - mu) * sc + bv1.y;
            mu = sm1.z * invN; var = sq1.z * invN - mu * mu;
            sc = rsqrtf(var + BN_EPS) * gv1.z; a1.z = (a1.z - mu) * sc + bv1.z;
            mu = sm1.w * invN; var = sq1.w * invN - mu * mu;
            sc = rsqrtf(var + BN_EPS) * gv1.w; a1.w = (a1.w - mu) * sc + bv1.w;
        }
        __syncthreads();   // prior iteration's frag reads complete
        f16x8 av;
        av[0] = (_Float16)a0.x; av[1] = (_Float16)a0.y;
        av[2] = (_Float16)a0.z; av[3] = (_Float16)a0.w;
        av[4] = (_Float16)a1.x; av[5] = (_Float16)a1.y;
        av[6] = (_Float16)a1.z; av[7] = (_Float16)a1.w;
        *(f16x8*)&As[ar][ac] = av;
        __syncthreads();
#pragma unroll
        for (int m = 0; m < 4; ++m) {
            f16x8 af = *(const f16x8*)&As[m * 16 + (lane & 15)][(lane >> 4) * 8];
            acc[m] = __builtin_amdgcn_mfma_f32_16x16x32_f16(af, bfr[s], acc[m], 0, 0, 0);
        }
    }

    // ---- epilogue: C col=lane&15 (+wv*16), row=(lane>>4)*4+i per 16-row subtile
#pragma unroll
    for (int m = 0; m < 4; ++m) {
#pragma unroll
        for (int i = 0; i < 4; ++i) {
            int r = row0 + m * 16 + (lane >> 4) * 4 + i;
            if (r < M) {
                out[(size_t)r * HID + col0 + wv * 16 + (lane & 15)] =
                    (_Float16)(acc[m][i] * dis[r]);
            }
        }
    }
}

// ---------------------------------------------------------------- gather
// One wave per node: s[n] = relu(dis[n]*(sum_{u in adj(n)} ht[u] + ht[n]) + b)
__global__ __launch_bounds__(256) void gather_relu(
    const _Float16* __restrict__ ht, const int* __restrict__ row_end,
    const int* __restrict__ adj, const float* __restrict__ dis,
    const float* __restrict__ b, float* __restrict__ s)
{
    int wid  = (blockIdx.x * 256 + threadIdx.x) >> 6;  // node id
    int lane = threadIdx.x & 63;
    if (wid >= N_NODES) return;
    const int n = wid;
    const int c = lane * 4;
    int beg = (n == 0) ? 0 : row_end[n - 1];
    int end = row_end[n];

    f16x4 sv = *(const f16x4*)(ht + (size_t)n * HID + c);  // self loop
    float4 acc = make_float4((float)sv[0], (float)sv[1], (float)sv[2], (float)sv[3]);

    int j = beg;
    while (j < end) {
        int m = end - j;
        if (m > 64) m = 64;
        int ul = adj[j + (lane < m ? lane : m - 1)];
        ul = min(ul, N_NODES - 1);   // no-op when adj valid; fault guard
        int k = 0;
        for (; k + 1 < m; k += 2) {
            int u0 = __shfl(ul, k);
            int u1 = __shfl(ul, k + 1);
            f16x4 v0 = *(const f16x4*)(ht + (size_t)u0 * HID + c);
            f16x4 v1 = *(const f16x4*)(ht + (size_t)u1 * HID + c);
            acc.x += (float)v0[0] + (float)v1[0];
            acc.y += (float)v0[1] + (float)v1[1];
            acc.z += (float)v0[2] + (float)v1[2];
            acc.w += (float)v0[3] + (float)v1[3];
        }
        if (k < m) {
            int u0 = __shfl(ul, k);
            f16x4 v0 = *(const f16x4*)(ht + (size_t)u0 * HID + c);
            acc.x += (float)v0[0];
            acc.y += (float)v0[1];
            acc.z += (float)v0[2];
            acc.w += (float)v0[3];
        }
        j += m;
    }

    float d = dis[n];
    float4 bv = ((const float4*)b)[lane];
    float4 o;
    o.x = fmaxf(fmaf(d, acc.x, bv.x), 0.f);
    o.y = fmaxf(fmaf(d, acc.y, bv.y), 0.f);
    o.z = fmaxf(fmaf(d, acc.z, bv.z), 0.f);
    o.w = fmaxf(fmaf(d, acc.w, bv.w), 0.f);
    *(float4*)(s + (size_t)n * HID + c) = o;
}

// ---------------------------------------------------------------- batch norm stats
// 2000 blocks x 25 rows: occupancy-fixed (was 256 blocks, 9% occupancy)
__global__ __launch_bounds__(256) void bn_stats(
    const float* __restrict__ h, float* __restrict__ stats, int rows_per_block)
{
    int c  = threadIdx.x;
    int r0 = blockIdx.x * rows_per_block;
    int r1 = min(r0 + rows_per_block, N_NODES);
    if (r0 >= N_NODES) return;
    float sum = 0.f, sq = 0.f;
    for (int r = r0; r < r1; ++r) {
        float v = h[(size_t)r * HID + c];
        sum += v;
        sq  = fmaf(v, v, sq);
    }
    atomicAdd(&stats[c], sum);
    atomicAdd(&stats[HID + c], sq);
}

// ---------------------------------------------------------------- pooling
__global__ __launch_bounds__(256) void pool_accum(
    const float* __restrict__ h, const int* __restrict__ batch,
    float* __restrict__ pool, float* __restrict__ cnt, int rows_per_block)
{
    int c  = threadIdx.x;
    int r0 = blockIdx.x * rows_per_block;
    int r1 = min(r0 + rows_per_block, N_NODES);
    if (r0 >= N_NODES) return;
    float acc = 0.f;
    int curg = batch[r0];
    for (int r = r0; r < r1; ++r) {
        int gidx = batch[r];
        if (gidx != curg) {
            atomicAdd(&pool[(size_t)curg * HID + c], acc);
            acc = 0.f;
            curg = gidx;
        }
        acc += h[(size_t)r * HID + c];
    }
    atomicAdd(&pool[(size_t)curg * HID + c], acc);
    if (c == 0) {
        int cacc = 0;
        int cg = batch[r0];
        for (int r = r0; r < r1; ++r) {
            int gidx = batch[r];
            if (gidx != cg) { atomicAdd(&cnt[cg], (float)cacc); cacc = 0; cg = gidx; }
            cacc++;
        }
        atomicAdd(&cnt[cg], (float)cacc);
    }
}

// head with fused BN2 apply: per-channel affine commutes with per-graph mean
__global__ __launch_bounds__(256) void final_head(
    const float* __restrict__ pool, const float* __restrict__ cnt,
    const float* __restrict__ stats, const float* __restrict__ g2,
    const float* __restrict__ be2, const float* __restrict__ Wf,
    const float* __restrict__ bf, float* __restrict__ out)
{
    __shared__ float p[HID];
    int gb = blockIdx.x;
    int c = threadIdx.x;
    const float invN = 1.0f / N_NODES;
    float inv = 1.0f / fmaxf(cnt[gb], 1.0f);
    float mu  = stats[c] * invN;
    float var = stats[HID + c] * invN - mu * mu;
    float sc  = rsqrtf(var + BN_EPS) * g2[c];
    p[c] = (pool[(size_t)gb * HID + c] * inv - mu) * sc + be2[c];
    __syncthreads();
    if (c < N_CLASSES) {
        float acc = bf[c];
        for (int k = 0; k < HID; ++k) acc = fmaf(p[k], Wf[k * N_CLASSES + c], acc);
        out[gb * N_CLASSES + c] = acc;
    }
}

// ---------------------------------------------------------------- launch
extern "C" void kernel_launch(void* const* d_in, const int* in_sizes, int n_in,
                              void* d_out, int out_size, void* d_ws, size_t ws_size,
                              hipStream_t stream) {
    const float* x   = (const float*)d_in[0];
    const int* eidx  = (const int*)d_in[1];
    const int* batch = (const int*)d_in[2];
    const float* W1  = (const float*)d_in[3];
    const float* b1  = (const float*)d_in[4];
    const float* W2  = (const float*)d_in[5];
    const float* b2  = (const float*)d_in[6];
    const float* W3  = (const float*)d_in[7];
    const float* b3  = (const float*)d_in[8];
    const float* g1  = (const float*)d_in[9];
    const float* be1 = (const float*)d_in[10];
    const float* g2  = (const float*)d_in[11];
    const float* be2 = (const float*)d_in[12];
    const float* Wf  = (const float*)d_in[13];
    const float* bf  = (const float*)d_in[14];
    float* out = (float*)d_out;

    const int* src = eidx;
    const int* dst = eidx + N_EDGES;

    // workspace layout (~80.7 MB, proven in round 10)
    _Float16* ht     = (_Float16*)d_ws;                      // 12.8M f16
    float* s         = (float*)(ht + (size_t)N_NODES * HID); // 12.8M f
    float* dis       = s + (size_t)N_NODES * HID;            // 50000 f
    float* stats     = dis + N_NODES;                        // 512 f
    float* pool      = stats + 2 * HID;                      // 16384 f
    float* cnt       = pool + (size_t)N_GRAPHS * HID;        // 64 f
    int* deg         = (int*)(cnt + N_GRAPHS);               // 50000 i
    int* row_start   = deg + N_NODES;                        // 50000 i
    int* chunk_sums  = row_start + N_NODES;                  // 256 i
    int* adj         = chunk_sums + 256;                     // 800000 i

    const int mTiles  = (N_NODES + 63) / 64;             // 782
    dim3 gemmGrid(mTiles, HID / 64);                     // 782 x 4
    const int nodeBlk = (N_NODES + 255) / 256;
    const int edgeBlk = (N_EDGES + 255) / 256;
    const int gatherBlk = (N_NODES * 64 + 255) / 256;    // 1 wave/node
    // occupancy fix: 25 rows/block -> 2000 blocks (was 196 rows, 256 blocks, 9% occ)
    const int redRows = 25;
    const int redBlk  = (N_NODES + redRows - 1) / redRows;   // 2000

    // ---- CSR build + degrees
    zero_f4<<<(N_NODES / 4 + 255) / 256, 256, 0, stream>>>((float4*)deg, N_NODES / 4);
    count_deg<<<edgeBlk, 256, 0, stream>>>(dst, deg);
    scan_chunk<<<NCHUNK, 256, 0, stream>>>(deg, row_start, chunk_sums, dis);
    scan_tops<<<1, 256, 0, stream>>>(chunk_sums);
    scan_add<<<nodeBlk, 256, 0, stream>>>(row_start, chunk_sums);
    fill_adj<<<edgeBlk, 256, 0, stream>>>(src, dst, row_start, adj);
    // row_start[n] is now END of bucket n

    // ---- layer 1
    gemm_mfma<IN_DIM, false><<<gemmGrid, 256, 0, stream>>>(
        x, W1, dis, nullptr, nullptr, nullptr, ht, N_NODES);
    gather_relu<<<gatherBlk, 256, 0, stream>>>(ht, row_start, adj, dis, b1, s);

    // ---- layer 2; BN1 stats (apply folded into layer-3 GEMM)
    gemm_mfma<HID, false><<<gemmGrid, 256, 0, stream>>>(
        s, W2, dis, nullptr, nullptr, nullptr, ht, N_NODES);
    gather_relu<<<gatherBlk, 256, 0, stream>>>(ht, row_start, adj, dis, b2, s);
    zero_f4<<<1, 256, 0, stream>>>((float4*)stats, 2 * HID / 4);
    bn_stats<<<redBlk, 256, 0, stream>>>(s, stats, redRows);

    // ---- layer 3 (BN1 fused into A-staging); BN2 stats (apply folded into head)
    gemm_mfma<HID, true><<<gemmGrid, 256, 0, stream>>>(
        s, W3, dis, stats, g1, be1, ht, N_NODES);
    gather_relu<<<gatherBlk, 256, 0, stream>>>(ht, row_start, adj, dis, b3, s);
    zero_f4<<<1, 256, 0, stream>>>((float4*)stats, 2 * HID / 4);
    bn_stats<<<redBlk, 256, 0, stream>>>(s, stats, redRows);

    // ---- pool (raw s; BN2 affine applied on pooled means in head) + head
    zero_f4<<<(N_GRAPHS * HID / 4 + N_GRAPHS / 4 + 255) / 256, 256, 0, stream>>>(
        (float4*)pool, N_GRAPHS * HID / 4 + N_GRAPHS / 4);
    pool_accum<<<redBlk, 256, 0, stream>>>(s, batch, pool, cnt, redRows);
    final_head<<<N_GRAPHS, 256, 0, stream>>>(pool, cnt, stats, g2, be2, Wf, bf, out);
}